// Round 4
// baseline (258.696 us; speedup 1.0000x reference)
//
#include <hip/hip_runtime.h>
#include <hip/hip_bf16.h>

typedef __bf16 bf16_t;
typedef __bf16 bf16x8 __attribute__((ext_vector_type(8)));
typedef float f32x4 __attribute__((ext_vector_type(4)));

#define SEQ_L 8192
#define DMODEL 1024
#define NHEAD 16
#define HDIM 64
static constexpr int MROWS = 2 * SEQ_L;  // B*L = 16384

// ---------------- async global->LDS (16B per lane) ----------------
__device__ __forceinline__ void async_cp16(const bf16_t* g, bf16_t* l) {
  __builtin_amdgcn_global_load_lds(
      (__attribute__((address_space(1))) void*)(void*)(g),
      (__attribute__((address_space(3))) void*)(void*)(l), 16, 0, 0);
}
__device__ __forceinline__ void wg_barrier() { asm volatile("s_barrier" ::: "memory"); }

// ---------------- f32 -> bf16 convert (vectorized) ----------------
__global__ __launch_bounds__(256) void f32_to_bf16_k(const float* __restrict__ in,
                                                     bf16_t* __restrict__ out, int n) {
  int i = (blockIdx.x * 256 + threadIdx.x) * 8;
  if (i >= n) return;
  float4 a = *(const float4*)(in + i);
  float4 b = *(const float4*)(in + i + 4);
  bf16x8 o;
  o[0] = (__bf16)a.x; o[1] = (__bf16)a.y; o[2] = (__bf16)a.z; o[3] = (__bf16)a.w;
  o[4] = (__bf16)b.x; o[5] = (__bf16)b.y; o[6] = (__bf16)b.z; o[7] = (__bf16)b.w;
  *(bf16x8*)(out + i) = o;
}

// ---------------- W (K x N f32) -> Wt (N x K bf16) ----------------
__global__ __launch_bounds__(256) void w_to_bt_k(
    const float* __restrict__ W0, const float* __restrict__ W1,
    const float* __restrict__ W2, const float* __restrict__ W3,
    bf16_t* __restrict__ T0, bf16_t* __restrict__ T1,
    bf16_t* __restrict__ T2, bf16_t* __restrict__ T3) {
  __shared__ float tile[32][33];
  const int z = blockIdx.z;
  const float* W = (z == 0) ? W0 : (z == 1) ? W1 : (z == 2) ? W2 : W3;
  bf16_t* T = (z == 0) ? T0 : (z == 1) ? T1 : (z == 2) ? T2 : T3;
  const int bx = blockIdx.x, by = blockIdx.y;
  const int tx = threadIdx.x, ty = threadIdx.y;  // 32 x 8
#pragma unroll
  for (int r = 0; r < 4; ++r)
    tile[ty + r * 8][tx] = W[(size_t)(by * 32 + ty + r * 8) * DMODEL + bx * 32 + tx];
  __syncthreads();
#pragma unroll
  for (int r = 0; r < 4; ++r)
    T[(size_t)(bx * 32 + ty + r * 8) * DMODEL + by * 32 + tx] = (bf16_t)tile[tx][ty + r * 8];
}

// ---------------- RoPE cos/sin table: tab[pos*32 + j] ----------------
__global__ __launch_bounds__(256) void rope_tab_k(float2* __restrict__ tab) {
  int i = blockIdx.x * 256 + threadIdx.x;  // pos*32 + j
  int pos = i >> 5, j = i & 31;
  double freq = pow(10000.0, -(double)j / 32.0);
  double ang = (double)pos * freq;
  tab[i] = make_float2((float)cos(ang), (float)sin(ang));
}

// ---------------- 256x256 8-phase bf16 GEMM (T1+T2+T3+T4+T5) ----------------
// C(M x N) = A(M x K) @ Bt(N x K)^T + bias, K = 1024, BK = 64, 8 waves (2M x 4N).
// Per K-tile: 4 phases, quadrant order (mh,nh) = (0,0),(0,1),(1,1),(1,0).
// Deep staging schedule (3 half-tiles in flight, vmcnt(6) at K-tile boundary):
//   ph0: stage A(m+1)h1 | ph2: stage B(m+2)h0 | ph3: stage B(m+2)h1 + A(m+2)h0
// Ledger at ph3: outstanding = A(m+1)h1 + B(m+2)h0/h1 + A(m+2)h0 = 8 loads;
// vmcnt(6) forces A(m+1)h1 (3-phase distance) and everything older.
// Safety: A(m+2)h0 overwrites As_[m&1] whose last ds-read (ph2) is drained by
// each wave's lgkmcnt before its ph2 MFMA + the ph2-end barrier.
// LDS st-swizzle: linear LDS dest, source chunk ^= row&7, same XOR on read.
// T1: 1D grid, bijective XCD chunking, col-fastest v so the NBY col-blocks
// sharing an A row-panel run consecutively on one XCD.
// MODE 0: fused QKV (N=3072), bias per range, RoPE on q/k, bf16 outs (stride 1024).
// MODE 1: f32 out + bias (O projection, N=1024).
template <int MODE, int NBY>
__global__ __launch_bounds__(512, 2) void gemm256(
    const bf16_t* __restrict__ A, const bf16_t* __restrict__ Bt,
    const float* __restrict__ b0, const float* __restrict__ b1,
    const float* __restrict__ b2, const float2* __restrict__ rope,
    void* __restrict__ O0, void* __restrict__ O1, void* __restrict__ O2) {
  constexpr int K = DMODEL;   // 1024
  constexpr int KT = K / 64;  // 16 K-tiles
  __shared__ bf16_t As_[2][256 * 64];
  __shared__ bf16_t Bs_[2][256 * 64];
  const int tid = threadIdx.x;
  const int lane = tid & 63;
  const int wave = tid >> 6;
  const int wm = wave >> 2;  // 0..1  (128-row half)
  const int wn = wave & 3;   // 0..3  (64-col span)

  // T1: XCD-chunked bijective swizzle; v col-fastest over (bx, by)
  const int nwg = gridDim.x;
  const int id = blockIdx.x;
  const int v = (id & 7) * (nwg >> 3) + (id >> 3);
  const size_t row0 = (size_t)(v / NBY) * 256;
  const int col0 = (v % NBY) * 256;

  const int fr = lane & 15;
  const int fkb = (lane >> 4) * 16;  // k-fragment byte offset within 64B k-half

  // staging precompute: thread covers rows srow(+64 for 2nd cp), swizzled chunk
  const int srow = tid >> 3;                        // 0..63
  const int schunk = (tid & 7) ^ ((tid >> 3) & 7);  // pre-swizzled source chunk
  const bf16_t* gA = A + (row0 + srow) * K + schunk * 8;
  const bf16_t* gB = Bt + ((size_t)col0 + srow) * K + schunk * 8;

#define STAGE_A(j, h)                                  \
  do {                                                 \
    const bf16_t* _g = gA + ((h)*128) * K + (j)*64;    \
    bf16_t* _l = &As_[(j)&1][(h)*8192 + tid * 8];      \
    async_cp16(_g, _l);                                \
    async_cp16(_g + 64 * K, _l + 4096);                \
  } while (0)
#define STAGE_B(j, h)                                  \
  do {                                                 \
    const bf16_t* _g = gB + ((h)*128) * K + (j)*64;    \
    bf16_t* _l = &Bs_[(j)&1][(h)*8192 + tid * 8];      \
    async_cp16(_g, _l);                                \
    async_cp16(_g + 64 * K, _l + 4096);                \
  } while (0)
#define RD(base, row, kh)                                                    \
  (*(const bf16x8*)((const char*)(base) +                                    \
                    (((row)*128 + ((kh)*64 + fkb)) ^ (((row)&7) << 4))))

  f32x4 acc[8][4] = {};
  bf16x8 af[4][2], bf0[2][2], bf1[2][2];

  // prologue: A(0),B(0) must land; in flight afterwards: B(1)h0,h1 + A(1)h0 = 6
  STAGE_A(0, 0); STAGE_A(0, 1);
  STAGE_B(0, 0); STAGE_B(0, 1);
  STAGE_B(1, 0); STAGE_B(1, 1);
  STAGE_A(1, 0);
  asm volatile("s_waitcnt vmcnt(6)" ::: "memory");
  wg_barrier();

  for (int m = 0; m < KT; ++m) {
    const bf16_t* Ac = &As_[m & 1][0];
    const bf16_t* Bc = &Bs_[m & 1][0];
    // ---- phase 0: quadrant (mh=0, nh=0) ----
#pragma unroll
    for (int f = 0; f < 4; ++f) {
      const int r = wm * 128 + f * 16 + fr;
      af[f][0] = RD(Ac, r, 0);
      af[f][1] = RD(Ac, r, 1);
    }
#pragma unroll
    for (int f = 0; f < 2; ++f) {
      const int r = wn * 64 + f * 16 + fr;
      bf0[f][0] = RD(Bc, r, 0);
      bf0[f][1] = RD(Bc, r, 1);
    }
    if (m + 1 < KT) STAGE_A(m + 1, 1);
    wg_barrier();
    __builtin_amdgcn_s_setprio(1);
#pragma unroll
    for (int f = 0; f < 4; ++f)
#pragma unroll
      for (int n = 0; n < 2; ++n)
#pragma unroll
        for (int kh = 0; kh < 2; ++kh)
          acc[f][n] = __builtin_amdgcn_mfma_f32_16x16x32_bf16(af[f][kh], bf0[n][kh], acc[f][n], 0, 0, 0);
    __builtin_amdgcn_s_setprio(0);
    wg_barrier();
    // ---- phase 1: quadrant (mh=0, nh=1) ----
#pragma unroll
    for (int f = 0; f < 2; ++f) {
      const int r = wn * 64 + (2 + f) * 16 + fr;
      bf1[f][0] = RD(Bc, r, 0);
      bf1[f][1] = RD(Bc, r, 1);
    }
    wg_barrier();
    __builtin_amdgcn_s_setprio(1);
#pragma unroll
    for (int f = 0; f < 4; ++f)
#pragma unroll
      for (int n = 0; n < 2; ++n)
#pragma unroll
        for (int kh = 0; kh < 2; ++kh)
          acc[f][2 + n] = __builtin_amdgcn_mfma_f32_16x16x32_bf16(af[f][kh], bf1[n][kh], acc[f][2 + n], 0, 0, 0);
    __builtin_amdgcn_s_setprio(0);
    wg_barrier();
    // ---- phase 2: quadrant (mh=1, nh=1); A-frags 4..7 overwrite af ----
#pragma unroll
    for (int f = 0; f < 4; ++f) {
      const int r = wm * 128 + (4 + f) * 16 + fr;
      af[f][0] = RD(Ac, r, 0);
      af[f][1] = RD(Ac, r, 1);
    }
    if (m + 2 < KT) STAGE_B(m + 2, 0);
    wg_barrier();
    __builtin_amdgcn_s_setprio(1);
#pragma unroll
    for (int f = 0; f < 4; ++f)
#pragma unroll
      for (int n = 0; n < 2; ++n)
#pragma unroll
        for (int kh = 0; kh < 2; ++kh)
          acc[4 + f][2 + n] = __builtin_amdgcn_mfma_f32_16x16x32_bf16(af[f][kh], bf1[n][kh], acc[4 + f][2 + n], 0, 0, 0);
    __builtin_amdgcn_s_setprio(0);
    wg_barrier();
    // ---- phase 3: quadrant (mh=1, nh=0); no ds_reads (bf0 kept in regs) ----
    if (m + 2 < KT) {
      STAGE_B(m + 2, 1);
      STAGE_A(m + 2, 0);  // safe: all As_[m&1] reads drained by ph2-end barrier
      asm volatile("s_waitcnt vmcnt(6)" ::: "memory");  // forces A(m+1)h1 + older
    } else if (m + 1 < KT) {
      asm volatile("s_waitcnt vmcnt(0)" ::: "memory");  // drain before last K-tile
    }
    wg_barrier();
    __builtin_amdgcn_s_setprio(1);
#pragma unroll
    for (int f = 0; f < 4; ++f)
#pragma unroll
      for (int n = 0; n < 2; ++n)
#pragma unroll
        for (int kh = 0; kh < 2; ++kh)
          acc[4 + f][n] = __builtin_amdgcn_mfma_f32_16x16x32_bf16(af[f][kh], bf0[n][kh], acc[4 + f][n], 0, 0, 0);
    __builtin_amdgcn_s_setprio(0);
    wg_barrier();
  }
#undef STAGE_A
#undef STAGE_B
#undef RD

  // ---- epilogue. C/D layout: col = lane&15, row = (lane>>4)*4 + reg ----
  const int lr = (lane >> 4) * 4;
  const int lc = lane & 15;
  const int gcol = col0 + wn * 64;  // aligned to one head (64)
  int which = 0;
  const float* bias = b0;
  int ocol = gcol;
  if constexpr (MODE == 0) {
    which = gcol >> 10;
    bias = (which == 0) ? b0 : (which == 1) ? b1 : b2;
    ocol = gcol - (which << 10);
  }
  const bool do_rope = (MODE == 0) && (which < 2);
  bf16_t* Cb = nullptr;
  float* Cf = nullptr;
  if constexpr (MODE == 0)
    Cb = (bf16_t*)((which == 0) ? O0 : (which == 1) ? O1 : O2);
  else
    Cf = (float*)O0;

#pragma unroll
  for (int mf = 0; mf < 8; ++mf) {
#pragma unroll
    for (int i = 0; i < 4; ++i) {
      const size_t grow = row0 + wm * 128 + mf * 16 + lr + i;
      float vv[4];
#pragma unroll
      for (int n = 0; n < 4; ++n) vv[n] = acc[mf][n][i] + bias[ocol + n * 16 + lc];
      if (do_rope) {
        // d(in-head) = n*16+lc; j = d>>1; partner d<32 ? d+32 (-sin) : d-32 (+sin)
        const int pos = (int)(grow & (size_t)(SEQ_L - 1));
        const float2* rp = rope + (size_t)pos * 32 + (lc >> 1);
        float rv[4];
#pragma unroll
        for (int n = 0; n < 4; ++n) {
          float2 cs = rp[n * 8];
          rv[n] = (n < 2) ? vv[n] * cs.x - vv[n + 2] * cs.y
                          : vv[n] * cs.x + vv[n - 2] * cs.y;
        }
#pragma unroll
        for (int n = 0; n < 4; ++n) vv[n] = rv[n];
      }
      const size_t cbase = grow * (size_t)DMODEL + ocol + lc;
      if constexpr (MODE == 1) {
#pragma unroll
        for (int n = 0; n < 4; ++n) Cf[cbase + n * 16] = vv[n];
      } else {
#pragma unroll
        for (int n = 0; n < 4; ++n) Cb[cbase + n * 16] = (bf16_t)vv[n];
      }
    }
  }
}

// ---------------- per-position head-mixing attention ----------------
__global__ __launch_bounds__(256) void attn_heads_k(const bf16_t* __restrict__ qb,
                                                    const bf16_t* __restrict__ kb,
                                                    const bf16_t* __restrict__ vb,
                                                    bf16_t* __restrict__ ob) {
  const int t = blockIdx.x * 256 + threadIdx.x;
  const int row = t >> 4;
  const int h = t & 15;
  const size_t rbase = (size_t)row * DMODEL;

  float q[HDIM];
#pragma unroll
  for (int j = 0; j < 8; ++j) {
    bf16x8 v8 = *(const bf16x8*)(qb + rbase + h * HDIM + j * 8);
#pragma unroll
    for (int u = 0; u < 8; ++u) q[j * 8 + u] = (float)v8[u];
  }
  float s[NHEAD];
#pragma unroll
  for (int e = 0; e < NHEAD; ++e) {
    float a = 0.f;
#pragma unroll
    for (int j = 0; j < 8; ++j) {
      bf16x8 k8 = *(const bf16x8*)(kb + rbase + e * HDIM + j * 8);
#pragma unroll
      for (int u = 0; u < 8; ++u) a += q[j * 8 + u] * (float)k8[u];
    }
    s[e] = a * 0.125f;
  }
  float mx = s[0];
#pragma unroll
  for (int e = 1; e < NHEAD; ++e) mx = fmaxf(mx, s[e]);
  float sum = 0.f;
#pragma unroll
  for (int e = 0; e < NHEAD; ++e) {
    s[e] = __expf(s[e] - mx);
    sum += s[e];
  }
  const float inv = 1.f / sum;
  float o[HDIM] = {};
#pragma unroll
  for (int e = 0; e < NHEAD; ++e) {
    const float w = s[e] * inv;
#pragma unroll
    for (int j = 0; j < 8; ++j) {
      bf16x8 v8 = *(const bf16x8*)(vb + rbase + e * HDIM + j * 8);
#pragma unroll
      for (int u = 0; u < 8; ++u) o[j * 8 + u] += w * (float)v8[u];
    }
  }
#pragma unroll
  for (int j = 0; j < 8; ++j) {
    bf16x8 st;
#pragma unroll
    for (int u = 0; u < 8; ++u) st[u] = (__bf16)o[j * 8 + u];
    *(bf16x8*)(ob + rbase + h * HDIM + j * 8) = st;
  }
}

extern "C" void kernel_launch(void* const* d_in, const int* in_sizes, int n_in,
                              void* d_out, int out_size, void* d_ws, size_t ws_size,
                              hipStream_t stream) {
  const float* x = (const float*)d_in[0];
  const float* Wq = (const float*)d_in[1];
  const float* bq = (const float*)d_in[2];
  const float* Wk = (const float*)d_in[3];
  const float* bk = (const float*)d_in[4];
  const float* Wv = (const float*)d_in[5];
  const float* bv = (const float*)d_in[6];
  const float* Wo = (const float*)d_in[7];
  const float* bo = (const float*)d_in[8];

  const int M = MROWS, N = DMODEL, K = DMODEL;

  char* p = (char*)d_ws;
  bf16_t* xb = (bf16_t*)p;    p += (size_t)M * K * 2;      // 32 MB
  bf16_t* Wqkvt = (bf16_t*)p; p += (size_t)3 * N * K * 2;  // 6 MB (q|k|v rows)
  bf16_t* Wot = (bf16_t*)p;   p += (size_t)N * K * 2;      // 2 MB
  bf16_t* qb = (bf16_t*)p;    p += (size_t)M * N * 2;      // 32 MB each
  bf16_t* kb = (bf16_t*)p;    p += (size_t)M * N * 2;
  bf16_t* vb = (bf16_t*)p;    p += (size_t)M * N * 2;
  bf16_t* ab = (bf16_t*)p;    p += (size_t)M * N * 2;
  float2* rope = (float2*)p;  p += (size_t)SEQ_L * 32 * sizeof(float2);  // 2 MB

  bf16_t* Wqt = Wqkvt;
  bf16_t* Wkt = Wqkvt + (size_t)N * K;
  bf16_t* Wvt = Wqkvt + (size_t)2 * N * K;

  f32_to_bf16_k<<<(M * K) / (256 * 8), 256, 0, stream>>>(x, xb, M * K);
  w_to_bt_k<<<dim3(32, 32, 4), dim3(32, 8), 0, stream>>>(Wq, Wk, Wv, Wo, Wqt, Wkt, Wvt, Wot);
  rope_tab_k<<<(SEQ_L * 32) / 256, 256, 0, stream>>>(rope);

  // fused QKV: C(16384 x 3072) = 768 blocks of 256^2 (1D grid, swizzled)
  gemm256<0, 12><<<768, 512, 0, stream>>>(
      xb, Wqkvt, bq, bk, bv, rope, (void*)qb, (void*)kb, (void*)vb);
  attn_heads_k<<<(M * NHEAD) / 256, 256, 0, stream>>>(qb, kb, vb, ab);
  gemm256<1, 4><<<256, 512, 0, stream>>>(
      ab, Wot, bo, nullptr, nullptr, nullptr, d_out, nullptr, nullptr);
}

// Round 5
// 246.358 us; speedup vs baseline: 1.0501x; 1.0501x over previous
//
#include <hip/hip_runtime.h>
#include <hip/hip_bf16.h>

typedef __bf16 bf16_t;
typedef __bf16 bf16x8 __attribute__((ext_vector_type(8)));
typedef float f32x4 __attribute__((ext_vector_type(4)));

#define SEQ_L 8192
#define DMODEL 1024
#define NHEAD 16
#define HDIM 64
static constexpr int MROWS = 2 * SEQ_L;  // B*L = 16384

// ---------------- async global->LDS (16B per lane) ----------------
__device__ __forceinline__ void async_cp16(const bf16_t* g, bf16_t* l) {
  __builtin_amdgcn_global_load_lds(
      (__attribute__((address_space(1))) void*)(void*)(g),
      (__attribute__((address_space(3))) void*)(void*)(l), 16, 0, 0);
}
// Raw barrier: does NOT drain vmcnt/lgkmcnt (unlike __syncthreads / asm with
// "memory" clobber, which makes the waitcnt-inserter emit vmcnt(0)).  T4 hinges
// on outstanding global_load_lds surviving across barriers.
__device__ __forceinline__ void wg_barrier() { __builtin_amdgcn_s_barrier(); }

// ---------------- f32 -> bf16 convert (vectorized) ----------------
__global__ __launch_bounds__(256) void f32_to_bf16_k(const float* __restrict__ in,
                                                     bf16_t* __restrict__ out, int n) {
  int i = (blockIdx.x * 256 + threadIdx.x) * 8;
  if (i >= n) return;
  float4 a = *(const float4*)(in + i);
  float4 b = *(const float4*)(in + i + 4);
  bf16x8 o;
  o[0] = (__bf16)a.x; o[1] = (__bf16)a.y; o[2] = (__bf16)a.z; o[3] = (__bf16)a.w;
  o[4] = (__bf16)b.x; o[5] = (__bf16)b.y; o[6] = (__bf16)b.z; o[7] = (__bf16)b.w;
  *(bf16x8*)(out + i) = o;
}

// ---------------- W (K x N f32) -> Wt (N x K bf16) ----------------
__global__ __launch_bounds__(256) void w_to_bt_k(
    const float* __restrict__ W0, const float* __restrict__ W1,
    const float* __restrict__ W2, const float* __restrict__ W3,
    bf16_t* __restrict__ T0, bf16_t* __restrict__ T1,
    bf16_t* __restrict__ T2, bf16_t* __restrict__ T3) {
  __shared__ float tile[32][33];
  const int z = blockIdx.z;
  const float* W = (z == 0) ? W0 : (z == 1) ? W1 : (z == 2) ? W2 : W3;
  bf16_t* T = (z == 0) ? T0 : (z == 1) ? T1 : (z == 2) ? T2 : T3;
  const int bx = blockIdx.x, by = blockIdx.y;
  const int tx = threadIdx.x, ty = threadIdx.y;  // 32 x 8
#pragma unroll
  for (int r = 0; r < 4; ++r)
    tile[ty + r * 8][tx] = W[(size_t)(by * 32 + ty + r * 8) * DMODEL + bx * 32 + tx];
  __syncthreads();
#pragma unroll
  for (int r = 0; r < 4; ++r)
    T[(size_t)(bx * 32 + ty + r * 8) * DMODEL + by * 32 + tx] = (bf16_t)tile[tx][ty + r * 8];
}

// ---------------- RoPE cos/sin table: tab[pos*32 + j] ----------------
__global__ __launch_bounds__(256) void rope_tab_k(float2* __restrict__ tab) {
  int i = blockIdx.x * 256 + threadIdx.x;  // pos*32 + j
  int pos = i >> 5, j = i & 31;
  double freq = pow(10000.0, -(double)j / 32.0);
  double ang = (double)pos * freq;
  tab[i] = make_float2((float)cos(ang), (float)sin(ang));
}

// ---------------- 256x256 8-phase bf16 GEMM (T2+T3+T4+T5) ----------------
// C(M x N) = A(M x K) @ Bt(N x K)^T + bias, K = 1024, BK = 64, 8 waves (2M x 4N).
// Per K-tile: 4 phases, quadrant order (mh,nh) = (0,0),(0,1),(1,1),(1,0).
// Deep staging (3 half-tiles in flight, per-wave ledger, 2 loads per STAGE):
//   ph0: stage A(m+1)h1 | ph2: stage B(m+2)h0 | ph3: stage B(m+2)h1 + A(m+2)h0
// At ph3 before wait: 14 outstanding; vmcnt(6) forces A(m+1)h1 + everything
// older (4-phase issue->wait distance); leaves B(m+2) + A(m+2)h0 in flight.
// Write-after-read safety: A(m+2)h0 overwrites As_[m&1] rows 0..127 whose last
// ds-read (ph2) is consumed by ph2's MFMA (compiler lgkmcnt) before the
// ph2-end barrier; the store is issued after that barrier.
// LDS st-swizzle: linear LDS dest, source chunk ^= row&7, same XOR on read.
// MODE 0: fused QKV (N=3072), bias per range, RoPE on q/k, bf16 outs (stride 1024).
// MODE 1: f32 out + bias (O projection, N=1024).
template <int MODE>
__global__ __launch_bounds__(512, 2) void gemm256(
    const bf16_t* __restrict__ A, const bf16_t* __restrict__ Bt,
    const float* __restrict__ b0, const float* __restrict__ b1,
    const float* __restrict__ b2, const float2* __restrict__ rope,
    void* __restrict__ O0, void* __restrict__ O1, void* __restrict__ O2) {
  constexpr int K = DMODEL;   // 1024
  constexpr int KT = K / 64;  // 16 K-tiles
  __shared__ bf16_t As_[2][256 * 64];
  __shared__ bf16_t Bs_[2][256 * 64];
  const int tid = threadIdx.x;
  const int lane = tid & 63;
  const int wave = tid >> 6;
  const int wm = wave >> 2;  // 0..1  (128-row half)
  const int wn = wave & 3;   // 0..3  (64-col span)
  const size_t row0 = (size_t)blockIdx.x * 256;
  const int col0 = blockIdx.y * 256;
  const int fr = lane & 15;
  const int fkb = (lane >> 4) * 16;  // k-fragment byte offset within 64B k-half

  // staging precompute: thread covers rows srow(+64 for 2nd cp), swizzled chunk
  const int srow = tid >> 3;                        // 0..63
  const int schunk = (tid & 7) ^ ((tid >> 3) & 7);  // pre-swizzled source chunk
  const bf16_t* gA = A + (row0 + srow) * K + schunk * 8;
  const bf16_t* gB = Bt + ((size_t)col0 + srow) * K + schunk * 8;

#define STAGE_A(j, h)                                  \
  do {                                                 \
    const bf16_t* _g = gA + ((h)*128) * K + (j)*64;    \
    bf16_t* _l = &As_[(j)&1][(h)*8192 + tid * 8];      \
    async_cp16(_g, _l);                                \
    async_cp16(_g + 64 * K, _l + 4096);                \
  } while (0)
#define STAGE_B(j, h)                                  \
  do {                                                 \
    const bf16_t* _g = gB + ((h)*128) * K + (j)*64;    \
    bf16_t* _l = &Bs_[(j)&1][(h)*8192 + tid * 8];      \
    async_cp16(_g, _l);                                \
    async_cp16(_g + 64 * K, _l + 4096);                \
  } while (0)
#define RD(base, row, kh)                                                    \
  (*(const bf16x8*)((const char*)(base) +                                    \
                    (((row)*128 + ((kh)*64 + fkb)) ^ (((row)&7) << 4))))
#define VMCNT(n) asm volatile("s_waitcnt vmcnt(" #n ")")

  f32x4 acc[8][4] = {};
  bf16x8 af[4][2], bf0[2][2], bf1[2][2];

  // prologue: A(0),B(0) must land; in flight afterwards: B(1)h0,h1 + A(1)h0 = 6
  STAGE_A(0, 0); STAGE_A(0, 1);
  STAGE_B(0, 0); STAGE_B(0, 1);
  STAGE_B(1, 0); STAGE_B(1, 1);
  STAGE_A(1, 0);
  VMCNT(6);
  wg_barrier();

  for (int m = 0; m < KT; ++m) {
    const bf16_t* Ac = &As_[m & 1][0];
    const bf16_t* Bc = &Bs_[m & 1][0];
    // ---- phase 0: quadrant (mh=0, nh=0) ----
#pragma unroll
    for (int f = 0; f < 4; ++f) {
      const int r = wm * 128 + f * 16 + fr;
      af[f][0] = RD(Ac, r, 0);
      af[f][1] = RD(Ac, r, 1);
    }
#pragma unroll
    for (int f = 0; f < 2; ++f) {
      const int r = wn * 64 + f * 16 + fr;
      bf0[f][0] = RD(Bc, r, 0);
      bf0[f][1] = RD(Bc, r, 1);
    }
    if (m + 1 < KT) STAGE_A(m + 1, 1);
    wg_barrier();
    __builtin_amdgcn_s_setprio(1);
#pragma unroll
    for (int f = 0; f < 4; ++f)
#pragma unroll
      for (int n = 0; n < 2; ++n)
#pragma unroll
        for (int kh = 0; kh < 2; ++kh)
          acc[f][n] = __builtin_amdgcn_mfma_f32_16x16x32_bf16(af[f][kh], bf0[n][kh], acc[f][n], 0, 0, 0);
    __builtin_amdgcn_s_setprio(0);
    wg_barrier();
    // ---- phase 1: quadrant (mh=0, nh=1) ----
#pragma unroll
    for (int f = 0; f < 2; ++f) {
      const int r = wn * 64 + (2 + f) * 16 + fr;
      bf1[f][0] = RD(Bc, r, 0);
      bf1[f][1] = RD(Bc, r, 1);
    }
    wg_barrier();
    __builtin_amdgcn_s_setprio(1);
#pragma unroll
    for (int f = 0; f < 4; ++f)
#pragma unroll
      for (int n = 0; n < 2; ++n)
#pragma unroll
        for (int kh = 0; kh < 2; ++kh)
          acc[f][2 + n] = __builtin_amdgcn_mfma_f32_16x16x32_bf16(af[f][kh], bf1[n][kh], acc[f][2 + n], 0, 0, 0);
    __builtin_amdgcn_s_setprio(0);
    wg_barrier();
    // ---- phase 2: quadrant (mh=1, nh=1); A-frags 4..7 overwrite af ----
#pragma unroll
    for (int f = 0; f < 4; ++f) {
      const int r = wm * 128 + (4 + f) * 16 + fr;
      af[f][0] = RD(Ac, r, 0);
      af[f][1] = RD(Ac, r, 1);
    }
    if (m + 2 < KT) STAGE_B(m + 2, 0);
    wg_barrier();
    __builtin_amdgcn_s_setprio(1);
#pragma unroll
    for (int f = 0; f < 4; ++f)
#pragma unroll
      for (int n = 0; n < 2; ++n)
#pragma unroll
        for (int kh = 0; kh < 2; ++kh)
          acc[4 + f][2 + n] = __builtin_amdgcn_mfma_f32_16x16x32_bf16(af[f][kh], bf1[n][kh], acc[4 + f][2 + n], 0, 0, 0);
    __builtin_amdgcn_s_setprio(0);
    wg_barrier();
    // ---- phase 3: quadrant (mh=1, nh=0); no ds_reads (bf0 kept in regs) ----
    if (m + 2 < KT) {
      STAGE_B(m + 2, 1);
      STAGE_A(m + 2, 0);
      VMCNT(6);  // forces A(m+1)h1 + older; leaves B(m+2),A(m+2)h0 in flight
    } else if (m + 1 < KT) {
      VMCNT(0);  // drain before last K-tile
    }
    wg_barrier();
    __builtin_amdgcn_s_setprio(1);
#pragma unroll
    for (int f = 0; f < 4; ++f)
#pragma unroll
      for (int n = 0; n < 2; ++n)
#pragma unroll
        for (int kh = 0; kh < 2; ++kh)
          acc[4 + f][n] = __builtin_amdgcn_mfma_f32_16x16x32_bf16(af[f][kh], bf0[n][kh], acc[4 + f][n], 0, 0, 0);
    __builtin_amdgcn_s_setprio(0);
    wg_barrier();
  }
#undef STAGE_A
#undef STAGE_B
#undef RD
#undef VMCNT

  // ---- epilogue. C/D layout: col = lane&15, row = (lane>>4)*4 + reg ----
  const int lr = (lane >> 4) * 4;
  const int lc = lane & 15;
  const int gcol = col0 + wn * 64;  // aligned to one head (64)
  int which = 0;
  const float* bias = b0;
  int ocol = gcol;
  if constexpr (MODE == 0) {
    which = gcol >> 10;
    bias = (which == 0) ? b0 : (which == 1) ? b1 : b2;
    ocol = gcol - (which << 10);
  }
  const bool do_rope = (MODE == 0) && (which < 2);
  bf16_t* Cb = nullptr;
  float* Cf = nullptr;
  if constexpr (MODE == 0)
    Cb = (bf16_t*)((which == 0) ? O0 : (which == 1) ? O1 : O2);
  else
    Cf = (float*)O0;

#pragma unroll
  for (int mf = 0; mf < 8; ++mf) {
#pragma unroll
    for (int i = 0; i < 4; ++i) {
      const size_t grow = row0 + wm * 128 + mf * 16 + lr + i;
      float vv[4];
#pragma unroll
      for (int n = 0; n < 4; ++n) vv[n] = acc[mf][n][i] + bias[ocol + n * 16 + lc];
      if (do_rope) {
        // d(in-head) = n*16+lc; j = d>>1; partner d<32 ? d+32 (-sin) : d-32 (+sin)
        const int pos = (int)(grow & (size_t)(SEQ_L - 1));
        const float2* rp = rope + (size_t)pos * 32 + (lc >> 1);
        float rv[4];
#pragma unroll
        for (int n = 0; n < 4; ++n) {
          float2 cs = rp[n * 8];
          rv[n] = (n < 2) ? vv[n] * cs.x - vv[n + 2] * cs.y
                          : vv[n] * cs.x + vv[n - 2] * cs.y;
        }
#pragma unroll
        for (int n = 0; n < 4; ++n) vv[n] = rv[n];
      }
      const size_t cbase = grow * (size_t)DMODEL + ocol + lc;
      if constexpr (MODE == 1) {
#pragma unroll
        for (int n = 0; n < 4; ++n) Cf[cbase + n * 16] = vv[n];
      } else {
#pragma unroll
        for (int n = 0; n < 4; ++n) Cb[cbase + n * 16] = (bf16_t)vv[n];
      }
    }
  }
}

// ---------------- per-position head-mixing attention ----------------
__global__ __launch_bounds__(256) void attn_heads_k(const bf16_t* __restrict__ qb,
                                                    const bf16_t* __restrict__ kb,
                                                    const bf16_t* __restrict__ vb,
                                                    bf16_t* __restrict__ ob) {
  const int t = blockIdx.x * 256 + threadIdx.x;
  const int row = t >> 4;
  const int h = t & 15;
  const size_t rbase = (size_t)row * DMODEL;

  float q[HDIM];
#pragma unroll
  for (int j = 0; j < 8; ++j) {
    bf16x8 v8 = *(const bf16x8*)(qb + rbase + h * HDIM + j * 8);
#pragma unroll
    for (int u = 0; u < 8; ++u) q[j * 8 + u] = (float)v8[u];
  }
  float s[NHEAD];
#pragma unroll
  for (int e = 0; e < NHEAD; ++e) {
    float a = 0.f;
#pragma unroll
    for (int j = 0; j < 8; ++j) {
      bf16x8 k8 = *(const bf16x8*)(kb + rbase + e * HDIM + j * 8);
#pragma unroll
      for (int u = 0; u < 8; ++u) a += q[j * 8 + u] * (float)k8[u];
    }
    s[e] = a * 0.125f;
  }
  float mx = s[0];
#pragma unroll
  for (int e = 1; e < NHEAD; ++e) mx = fmaxf(mx, s[e]);
  float sum = 0.f;
#pragma unroll
  for (int e = 0; e < NHEAD; ++e) {
    s[e] = __expf(s[e] - mx);
    sum += s[e];
  }
  const float inv = 1.f / sum;
  float o[HDIM] = {};
#pragma unroll
  for (int e = 0; e < NHEAD; ++e) {
    const float w = s[e] * inv;
#pragma unroll
    for (int j = 0; j < 8; ++j) {
      bf16x8 v8 = *(const bf16x8*)(vb + rbase + e * HDIM + j * 8);
#pragma unroll
      for (int u = 0; u < 8; ++u) o[j * 8 + u] += w * (float)v8[u];
    }
  }
#pragma unroll
  for (int j = 0; j < 8; ++j) {
    bf16x8 st;
#pragma unroll
    for (int u = 0; u < 8; ++u) st[u] = (__bf16)o[j * 8 + u];
    *(bf16x8*)(ob + rbase + h * HDIM + j * 8) = st;
  }
}

extern "C" void kernel_launch(void* const* d_in, const int* in_sizes, int n_in,
                              void* d_out, int out_size, void* d_ws, size_t ws_size,
                              hipStream_t stream) {
  const float* x = (const float*)d_in[0];
  const float* Wq = (const float*)d_in[1];
  const float* bq = (const float*)d_in[2];
  const float* Wk = (const float*)d_in[3];
  const float* bk = (const float*)d_in[4];
  const float* Wv = (const float*)d_in[5];
  const float* bv = (const float*)d_in[6];
  const float* Wo = (const float*)d_in[7];
  const float* bo = (const float*)d_in[8];

  const int M = MROWS, N = DMODEL, K = DMODEL;

  char* p = (char*)d_ws;
  bf16_t* xb = (bf16_t*)p;    p += (size_t)M * K * 2;      // 32 MB
  bf16_t* Wqkvt = (bf16_t*)p; p += (size_t)3 * N * K * 2;  // 6 MB (q|k|v rows)
  bf16_t* Wot = (bf16_t*)p;   p += (size_t)N * K * 2;      // 2 MB
  bf16_t* qb = (bf16_t*)p;    p += (size_t)M * N * 2;      // 32 MB each
  bf16_t* kb = (bf16_t*)p;    p += (size_t)M * N * 2;
  bf16_t* vb = (bf16_t*)p;    p += (size_t)M * N * 2;
  bf16_t* ab = (bf16_t*)p;    p += (size_t)M * N * 2;
  float2* rope = (float2*)p;  p += (size_t)SEQ_L * 32 * sizeof(float2);  // 2 MB

  bf16_t* Wqt = Wqkvt;
  bf16_t* Wkt = Wqkvt + (size_t)N * K;
  bf16_t* Wvt = Wqkvt + (size_t)2 * N * K;

  f32_to_bf16_k<<<(M * K) / (256 * 8), 256, 0, stream>>>(x, xb, M * K);
  w_to_bt_k<<<dim3(32, 32, 4), dim3(32, 8), 0, stream>>>(Wq, Wk, Wv, Wo, Wqt, Wkt, Wvt, Wot);
  rope_tab_k<<<(SEQ_L * 32) / 256, 256, 0, stream>>>(rope);

  // fused QKV: C(16384 x 3072), 64 x 12 blocks of 256^2
  gemm256<0><<<dim3(M / 256, (3 * N) / 256), 512, 0, stream>>>(
      xb, Wqkvt, bq, bk, bv, rope, (void*)qb, (void*)kb, (void*)vb);
  attn_heads_k<<<(M * NHEAD) / 256, 256, 0, stream>>>(qb, kb, vb, ab);
  gemm256<1><<<dim3(M / 256, N / 256), 512, 0, stream>>>(
      ab, Wot, bo, nullptr, nullptr, nullptr, d_out, nullptr, nullptr);
}

// Round 6
// 245.551 us; speedup vs baseline: 1.0535x; 1.0033x over previous
//
#include <hip/hip_runtime.h>
#include <hip/hip_bf16.h>

typedef __bf16 bf16_t;
typedef __bf16 bf16x8 __attribute__((ext_vector_type(8)));
typedef float f32x4 __attribute__((ext_vector_type(4)));

#define SEQ_L 8192
#define DMODEL 1024
#define NHEAD 16
#define HDIM 64
static constexpr int MROWS = 2 * SEQ_L;  // B*L = 16384

// ---------------- async global->LDS (16B per lane) ----------------
__device__ __forceinline__ void async_cp16(const bf16_t* g, bf16_t* l) {
  __builtin_amdgcn_global_load_lds(
      (__attribute__((address_space(1))) void*)(void*)(g),
      (__attribute__((address_space(3))) void*)(void*)(l), 16, 0, 0);
}
// Raw barrier: does NOT drain vmcnt (T4 hinges on staged loads surviving it).
__device__ __forceinline__ void wg_barrier() { __builtin_amdgcn_s_barrier(); }

// ---------------- f32 -> bf16 convert (vectorized) ----------------
__global__ __launch_bounds__(256) void f32_to_bf16_k(const float* __restrict__ in,
                                                     bf16_t* __restrict__ out, int n) {
  int i = (blockIdx.x * 256 + threadIdx.x) * 8;
  if (i >= n) return;
  float4 a = *(const float4*)(in + i);
  float4 b = *(const float4*)(in + i + 4);
  bf16x8 o;
  o[0] = (__bf16)a.x; o[1] = (__bf16)a.y; o[2] = (__bf16)a.z; o[3] = (__bf16)a.w;
  o[4] = (__bf16)b.x; o[5] = (__bf16)b.y; o[6] = (__bf16)b.z; o[7] = (__bf16)b.w;
  *(bf16x8*)(out + i) = o;
}

// ---------------- W (K x N f32) -> Wt (N x K bf16) ----------------
__global__ __launch_bounds__(256) void w_to_bt_k(
    const float* __restrict__ W0, const float* __restrict__ W1,
    const float* __restrict__ W2, const float* __restrict__ W3,
    bf16_t* __restrict__ T0, bf16_t* __restrict__ T1,
    bf16_t* __restrict__ T2, bf16_t* __restrict__ T3) {
  __shared__ float tile[32][33];
  const int z = blockIdx.z;
  const float* W = (z == 0) ? W0 : (z == 1) ? W1 : (z == 2) ? W2 : W3;
  bf16_t* T = (z == 0) ? T0 : (z == 1) ? T1 : (z == 2) ? T2 : T3;
  const int bx = blockIdx.x, by = blockIdx.y;
  const int tx = threadIdx.x, ty = threadIdx.y;  // 32 x 8
#pragma unroll
  for (int r = 0; r < 4; ++r)
    tile[ty + r * 8][tx] = W[(size_t)(by * 32 + ty + r * 8) * DMODEL + bx * 32 + tx];
  __syncthreads();
#pragma unroll
  for (int r = 0; r < 4; ++r)
    T[(size_t)(bx * 32 + ty + r * 8) * DMODEL + by * 32 + tx] = (bf16_t)tile[tx][ty + r * 8];
}

// ---------------- RoPE cos/sin table: tab[pos*32 + j] ----------------
__global__ __launch_bounds__(256) void rope_tab_k(float2* __restrict__ tab) {
  int i = blockIdx.x * 256 + threadIdx.x;  // pos*32 + j
  int pos = i >> 5, j = i & 31;
  double freq = pow(10000.0, -(double)j / 32.0);
  double ang = (double)pos * freq;
  tab[i] = make_float2((float)cos(ang), (float)sin(ang));
}

// ---------------- 256x256 bf16 GEMM, single-region K-tile ----------------
// C(M x N) = A(M x K) @ Bt(N x K)^T + bias, K=1024, BK=64, 8 waves (2M x 4N).
// Per K-tile ONE region: issue all 24 ds_read_b128 (B 8, A-h0 8, A-h1 8), then
// 64 MFMA; the backend interleaves counted lgkmcnt waits so LDS reads overlap
// MFMA issue.  Two barriers per K-tile at the boundary only:
//   MFMA done -> barrier#1 (all waves' reads of buf[m&1] consumed)
//   -> stage tile m+2 into buf[m&1] (8 global_load_lds, WAR-safe)
//   -> vmcnt(8): forces stage(m+1) (issued one full tile ago; no stall),
//      leaves stage(m+2) in flight -> barrier#2 -> next tile reads.
// sched_barrier(0) after each barrier pins the (compiler-invisible) LDS-DMA
// ordering: next-tile ds_reads must not hoist above vmcnt+barrier.
// LDS st-swizzle: linear LDS dest, source chunk ^= row&7, same XOR on read.
// MODE 0: fused QKV (N=3072), bias per range, RoPE on q/k, bf16 outs (stride 1024).
// MODE 1: f32 out + bias (O projection, N=1024).
template <int MODE>
__global__ __launch_bounds__(512, 2) void gemm256(
    const bf16_t* __restrict__ A, const bf16_t* __restrict__ Bt,
    const float* __restrict__ b0, const float* __restrict__ b1,
    const float* __restrict__ b2, const float2* __restrict__ rope,
    void* __restrict__ O0, void* __restrict__ O1, void* __restrict__ O2) {
  constexpr int K = DMODEL;   // 1024
  constexpr int KT = K / 64;  // 16 K-tiles
  __shared__ bf16_t As_[2][256 * 64];
  __shared__ bf16_t Bs_[2][256 * 64];
  const int tid = threadIdx.x;
  const int lane = tid & 63;
  const int wave = tid >> 6;
  const int wm = wave >> 2;  // 0..1  (128-row half)
  const int wn = wave & 3;   // 0..3  (64-col span)
  const size_t row0 = (size_t)blockIdx.x * 256;
  const int col0 = blockIdx.y * 256;
  const int fr = lane & 15;
  const int fkb = (lane >> 4) * 16;  // k-fragment byte offset within 64B k-half

  // staging precompute: thread covers rows srow(+64 for 2nd cp), swizzled chunk
  const int srow = tid >> 3;                        // 0..63
  const int schunk = (tid & 7) ^ ((tid >> 3) & 7);  // pre-swizzled source chunk
  const bf16_t* gA = A + (row0 + srow) * K + schunk * 8;
  const bf16_t* gB = Bt + ((size_t)col0 + srow) * K + schunk * 8;

#define STAGE_A(j, h)                                  \
  do {                                                 \
    const bf16_t* _g = gA + ((h)*128) * K + (j)*64;    \
    bf16_t* _l = &As_[(j)&1][(h)*8192 + tid * 8];      \
    async_cp16(_g, _l);                                \
    async_cp16(_g + 64 * K, _l + 4096);                \
  } while (0)
#define STAGE_B(j, h)                                  \
  do {                                                 \
    const bf16_t* _g = gB + ((h)*128) * K + (j)*64;    \
    bf16_t* _l = &Bs_[(j)&1][(h)*8192 + tid * 8];      \
    async_cp16(_g, _l);                                \
    async_cp16(_g + 64 * K, _l + 4096);                \
  } while (0)
#define STAGE_T(j)                                     \
  do {                                                 \
    STAGE_A(j, 0); STAGE_A(j, 1);                      \
    STAGE_B(j, 0); STAGE_B(j, 1);                      \
  } while (0)
#define RD(base, row, kh)                                                    \
  (*(const bf16x8*)((const char*)(base) +                                    \
                    (((row)*128 + ((kh)*64 + fkb)) ^ (((row)&7) << 4))))
#define VMCNT(n) asm volatile("s_waitcnt vmcnt(" #n ")")
#define SCHED_FENCE() __builtin_amdgcn_sched_barrier(0)

  f32x4 acc[8][4] = {};
  bf16x8 a0[4][2], a1[4][2], bfr[4][2];

  // prologue: stage tiles 0 and 1; tile 0 must land, tile 1 stays in flight
  STAGE_T(0);
  STAGE_T(1);
  VMCNT(8);
  wg_barrier();
  SCHED_FENCE();

  for (int m = 0; m < KT; ++m) {
    const bf16_t* Ac = &As_[m & 1][0];
    const bf16_t* Bc = &Bs_[m & 1][0];
    // ---- all fragment reads for this K-tile (24 x ds_read_b128) ----
#pragma unroll
    for (int f = 0; f < 4; ++f) {
      const int r = wn * 64 + f * 16 + fr;
      bfr[f][0] = RD(Bc, r, 0);
      bfr[f][1] = RD(Bc, r, 1);
    }
#pragma unroll
    for (int f = 0; f < 4; ++f) {
      const int r = wm * 128 + f * 16 + fr;
      a0[f][0] = RD(Ac, r, 0);
      a0[f][1] = RD(Ac, r, 1);
    }
#pragma unroll
    for (int f = 0; f < 4; ++f) {
      const int r = wm * 128 + (4 + f) * 16 + fr;
      a1[f][0] = RD(Ac, r, 0);
      a1[f][1] = RD(Ac, r, 1);
    }
    // ---- 64 MFMA; backend interleaves lgkmcnt-counted waits with issue ----
    __builtin_amdgcn_s_setprio(1);
#pragma unroll
    for (int f = 0; f < 4; ++f)
#pragma unroll
      for (int n = 0; n < 4; ++n)
#pragma unroll
        for (int kh = 0; kh < 2; ++kh)
          acc[f][n] = __builtin_amdgcn_mfma_f32_16x16x32_bf16(a0[f][kh], bfr[n][kh], acc[f][n], 0, 0, 0);
#pragma unroll
    for (int f = 0; f < 4; ++f)
#pragma unroll
      for (int n = 0; n < 4; ++n)
#pragma unroll
        for (int kh = 0; kh < 2; ++kh)
          acc[4 + f][n] = __builtin_amdgcn_mfma_f32_16x16x32_bf16(a1[f][kh], bfr[n][kh], acc[4 + f][n], 0, 0, 0);
    __builtin_amdgcn_s_setprio(0);
    wg_barrier();  // all waves' reads of buf[m&1] are consumed
    SCHED_FENCE();
    if (m + 2 < KT) {
      STAGE_T(m + 2);  // overwrite buf[m&1] (WAR-safe after barrier)
      VMCNT(8);        // forces stage(m+1) landed; leaves stage(m+2) in flight
    } else {
      VMCNT(0);        // tail: force stage(m+1) landed
    }
    wg_barrier();
    SCHED_FENCE();
  }
#undef STAGE_A
#undef STAGE_B
#undef STAGE_T
#undef RD
#undef VMCNT
#undef SCHED_FENCE

  // ---- epilogue. C/D layout: col = lane&15, row = (lane>>4)*4 + reg ----
  const int lr = (lane >> 4) * 4;
  const int lc = lane & 15;
  const int gcol = col0 + wn * 64;  // aligned to one head (64)
  int which = 0;
  const float* bias = b0;
  int ocol = gcol;
  if constexpr (MODE == 0) {
    which = gcol >> 10;
    bias = (which == 0) ? b0 : (which == 1) ? b1 : b2;
    ocol = gcol - (which << 10);
  }
  const bool do_rope = (MODE == 0) && (which < 2);
  bf16_t* Cb = nullptr;
  float* Cf = nullptr;
  if constexpr (MODE == 0)
    Cb = (bf16_t*)((which == 0) ? O0 : (which == 1) ? O1 : O2);
  else
    Cf = (float*)O0;

#pragma unroll
  for (int mf = 0; mf < 8; ++mf) {
#pragma unroll
    for (int i = 0; i < 4; ++i) {
      const size_t grow = row0 + wm * 128 + mf * 16 + lr + i;
      float vv[4];
#pragma unroll
      for (int n = 0; n < 4; ++n) vv[n] = acc[mf][n][i] + bias[ocol + n * 16 + lc];
      if (do_rope) {
        // d(in-head) = n*16+lc; j = d>>1; partner d<32 ? d+32 (-sin) : d-32 (+sin)
        const int pos = (int)(grow & (size_t)(SEQ_L - 1));
        const float2* rp = rope + (size_t)pos * 32 + (lc >> 1);
        float rv[4];
#pragma unroll
        for (int n = 0; n < 4; ++n) {
          float2 cs = rp[n * 8];
          rv[n] = (n < 2) ? vv[n] * cs.x - vv[n + 2] * cs.y
                          : vv[n] * cs.x + vv[n - 2] * cs.y;
        }
#pragma unroll
        for (int n = 0; n < 4; ++n) vv[n] = rv[n];
      }
      const size_t cbase = grow * (size_t)DMODEL + ocol + lc;
      if constexpr (MODE == 1) {
#pragma unroll
        for (int n = 0; n < 4; ++n) Cf[cbase + n * 16] = vv[n];
      } else {
#pragma unroll
        for (int n = 0; n < 4; ++n) Cb[cbase + n * 16] = (bf16_t)vv[n];
      }
    }
  }
}

// ---------------- per-position head-mixing attention ----------------
__global__ __launch_bounds__(256) void attn_heads_k(const bf16_t* __restrict__ qb,
                                                    const bf16_t* __restrict__ kb,
                                                    const bf16_t* __restrict__ vb,
                                                    bf16_t* __restrict__ ob) {
  const int t = blockIdx.x * 256 + threadIdx.x;
  const int row = t >> 4;
  const int h = t & 15;
  const size_t rbase = (size_t)row * DMODEL;

  float q[HDIM];
#pragma unroll
  for (int j = 0; j < 8; ++j) {
    bf16x8 v8 = *(const bf16x8*)(qb + rbase + h * HDIM + j * 8);
#pragma unroll
    for (int u = 0; u < 8; ++u) q[j * 8 + u] = (float)v8[u];
  }
  float s[NHEAD];
#pragma unroll
  for (int e = 0; e < NHEAD; ++e) {
    float a = 0.f;
#pragma unroll
    for (int j = 0; j < 8; ++j) {
      bf16x8 k8 = *(const bf16x8*)(kb + rbase + e * HDIM + j * 8);
#pragma unroll
      for (int u = 0; u < 8; ++u) a += q[j * 8 + u] * (float)k8[u];
    }
    s[e] = a * 0.125f;
  }
  float mx = s[0];
#pragma unroll
  for (int e = 1; e < NHEAD; ++e) mx = fmaxf(mx, s[e]);
  float sum = 0.f;
#pragma unroll
  for (int e = 0; e < NHEAD; ++e) {
    s[e] = __expf(s[e] - mx);
    sum += s[e];
  }
  const float inv = 1.f / sum;
  float o[HDIM] = {};
#pragma unroll
  for (int e = 0; e < NHEAD; ++e) {
    const float w = s[e] * inv;
#pragma unroll
    for (int j = 0; j < 8; ++j) {
      bf16x8 v8 = *(const bf16x8*)(vb + rbase + e * HDIM + j * 8);
#pragma unroll
      for (int u = 0; u < 8; ++u) o[j * 8 + u] += w * (float)v8[u];
    }
  }
#pragma unroll
  for (int j = 0; j < 8; ++j) {
    bf16x8 st;
#pragma unroll
    for (int u = 0; u < 8; ++u) st[u] = (__bf16)o[j * 8 + u];
    *(bf16x8*)(ob + rbase + h * HDIM + j * 8) = st;
  }
}

extern "C" void kernel_launch(void* const* d_in, const int* in_sizes, int n_in,
                              void* d_out, int out_size, void* d_ws, size_t ws_size,
                              hipStream_t stream) {
  const float* x = (const float*)d_in[0];
  const float* Wq = (const float*)d_in[1];
  const float* bq = (const float*)d_in[2];
  const float* Wk = (const float*)d_in[3];
  const float* bk = (const float*)d_in[4];
  const float* Wv = (const float*)d_in[5];
  const float* bv = (const float*)d_in[6];
  const float* Wo = (const float*)d_in[7];
  const float* bo = (const float*)d_in[8];

  const int M = MROWS, N = DMODEL, K = DMODEL;

  char* p = (char*)d_ws;
  bf16_t* xb = (bf16_t*)p;    p += (size_t)M * K * 2;      // 32 MB
  bf16_t* Wqkvt = (bf16_t*)p; p += (size_t)3 * N * K * 2;  // 6 MB (q|k|v rows)
  bf16_t* Wot = (bf16_t*)p;   p += (size_t)N * K * 2;      // 2 MB
  bf16_t* qb = (bf16_t*)p;    p += (size_t)M * N * 2;      // 32 MB each
  bf16_t* kb = (bf16_t*)p;    p += (size_t)M * N * 2;
  bf16_t* vb = (bf16_t*)p;    p += (size_t)M * N * 2;
  bf16_t* ab = (bf16_t*)p;    p += (size_t)M * N * 2;
  float2* rope = (float2*)p;  p += (size_t)SEQ_L * 32 * sizeof(float2);  // 2 MB

  bf16_t* Wqt = Wqkvt;
  bf16_t* Wkt = Wqkvt + (size_t)N * K;
  bf16_t* Wvt = Wqkvt + (size_t)2 * N * K;

  f32_to_bf16_k<<<(M * K) / (256 * 8), 256, 0, stream>>>(x, xb, M * K);
  w_to_bt_k<<<dim3(32, 32, 4), dim3(32, 8), 0, stream>>>(Wq, Wk, Wv, Wo, Wqt, Wkt, Wvt, Wot);
  rope_tab_k<<<(SEQ_L * 32) / 256, 256, 0, stream>>>(rope);

  // fused QKV: C(16384 x 3072), 64 x 12 blocks of 256^2
  gemm256<0><<<dim3(M / 256, (3 * N) / 256), 512, 0, stream>>>(
      xb, Wqkvt, bq, bk, bv, rope, (void*)qb, (void*)kb, (void*)vb);
  attn_heads_k<<<(M * NHEAD) / 256, 256, 0, stream>>>(qb, kb, vb, ab);
  gemm256<1><<<dim3(M / 256, N / 256), 512, 0, stream>>>(
      ab, Wot, bo, nullptr, nullptr, nullptr, d_out, nullptr, nullptr);
}

// Round 7
// 230.454 us; speedup vs baseline: 1.1225x; 1.0655x over previous
//
#include <hip/hip_runtime.h>
#include <hip/hip_bf16.h>

typedef __bf16 bf16_t;
typedef __bf16 bf16x8 __attribute__((ext_vector_type(8)));
typedef float f32x4 __attribute__((ext_vector_type(4)));

#define SEQ_L 8192
#define DMODEL 1024
#define NHEAD 16
#define HDIM 64
static constexpr int MROWS = 2 * SEQ_L;  // B*L = 16384

// ---------------- async global->LDS (16B per lane) ----------------
__device__ __forceinline__ void async_cp16(const bf16_t* g, bf16_t* l) {
  __builtin_amdgcn_global_load_lds(
      (__attribute__((address_space(1))) void*)(void*)(g),
      (__attribute__((address_space(3))) void*)(void*)(l), 16, 0, 0);
}
// Raw barrier: does NOT drain vmcnt/lgkmcnt.
__device__ __forceinline__ void wg_barrier() { __builtin_amdgcn_s_barrier(); }

// ---------------- f32 -> bf16 convert (vectorized) ----------------
__global__ __launch_bounds__(256) void f32_to_bf16_k(const float* __restrict__ in,
                                                     bf16_t* __restrict__ out, int n) {
  int i = (blockIdx.x * 256 + threadIdx.x) * 8;
  if (i >= n) return;
  float4 a = *(const float4*)(in + i);
  float4 b = *(const float4*)(in + i + 4);
  bf16x8 o;
  o[0] = (__bf16)a.x; o[1] = (__bf16)a.y; o[2] = (__bf16)a.z; o[3] = (__bf16)a.w;
  o[4] = (__bf16)b.x; o[5] = (__bf16)b.y; o[6] = (__bf16)b.z; o[7] = (__bf16)b.w;
  *(bf16x8*)(out + i) = o;
}

// ---------------- W (K x N f32) -> Wt (N x K bf16) ----------------
__global__ __launch_bounds__(256) void w_to_bt_k(
    const float* __restrict__ W0, const float* __restrict__ W1,
    const float* __restrict__ W2, const float* __restrict__ W3,
    bf16_t* __restrict__ T0, bf16_t* __restrict__ T1,
    bf16_t* __restrict__ T2, bf16_t* __restrict__ T3) {
  __shared__ float tile[32][33];
  const int z = blockIdx.z;
  const float* W = (z == 0) ? W0 : (z == 1) ? W1 : (z == 2) ? W2 : W3;
  bf16_t* T = (z == 0) ? T0 : (z == 1) ? T1 : (z == 2) ? T2 : T3;
  const int bx = blockIdx.x, by = blockIdx.y;
  const int tx = threadIdx.x, ty = threadIdx.y;  // 32 x 8
#pragma unroll
  for (int r = 0; r < 4; ++r)
    tile[ty + r * 8][tx] = W[(size_t)(by * 32 + ty + r * 8) * DMODEL + bx * 32 + tx];
  __syncthreads();
#pragma unroll
  for (int r = 0; r < 4; ++r)
    T[(size_t)(bx * 32 + ty + r * 8) * DMODEL + by * 32 + tx] = (bf16_t)tile[tx][ty + r * 8];
}

// ---------------- RoPE cos/sin table: tab[pos*32 + j] ----------------
__global__ __launch_bounds__(256) void rope_tab_k(float2* __restrict__ tab) {
  int i = blockIdx.x * 256 + threadIdx.x;  // pos*32 + j
  int pos = i >> 5, j = i & 31;
  double freq = pow(10000.0, -(double)j / 32.0);
  double ang = (double)pos * freq;
  tab[i] = make_float2((float)cos(ang), (float)sin(ang));
}

// ---------------- 128x128 bf16 GEMM, 4 blocks/CU anti-phase ----------------
// C(M x N) = A(M x K) @ Bt(N x K)^T + bias, K=1024, BK=64, 4 waves (2M x 2N),
// per-wave 64x64 output (acc[4][4] = 64 regs).  SINGLE-buffered 32 KiB LDS +
// <=128 combined regs (launch_bounds(256,4)) => 4 independent blocks per CU.
// Per-block schedule is serial per K-tile; cross-block anti-phase keeps the
// MFMA / LDS / DMA pipes overlapped (no intra-block pipelining needed).
// Per K-tile: {reads kh0 + 16 MFMA, reads kh1 + 16 MFMA} -> lgkm0 -> bar ->
// stage(m+1) same buffer (WAR-safe) -> vmcnt(0) -> bar.
// LDS st-swizzle: linear LDS dest, source chunk ^= row&7, same XOR on read.
// MODE 0: fused QKV (N=3072), bias per range, RoPE on q/k, bf16 outs (stride 1024).
// MODE 1: f32 out + bias (O projection, N=1024).
template <int MODE>
__global__ __launch_bounds__(256, 4) void gemm128(
    const bf16_t* __restrict__ A, const bf16_t* __restrict__ Bt,
    const float* __restrict__ b0, const float* __restrict__ b1,
    const float* __restrict__ b2, const float2* __restrict__ rope,
    void* __restrict__ O0, void* __restrict__ O1, void* __restrict__ O2) {
  constexpr int K = DMODEL;   // 1024
  constexpr int KT = K / 64;  // 16 K-tiles
  __shared__ bf16_t As_[128 * 64];
  __shared__ bf16_t Bs_[128 * 64];
  const int tid = threadIdx.x;
  const int lane = tid & 63;
  const int wave = tid >> 6;  // 0..3
  const int wm = wave >> 1;   // 0..1 (64-row half)
  const int wn = wave & 1;    // 0..1 (64-col half)
  const size_t row0 = (size_t)blockIdx.x * 128;
  const int col0 = blockIdx.y * 128;
  const int fr = lane & 15;
  const int fkb = (lane >> 4) * 16;  // 16B k-chunk within 64B k-half

  // staging: wave w, load l covers rows w*32 + l*8 + (lane>>3); chunk pre-swizzled
  const int srow = lane >> 3;                       // 0..7
  const int schunk = (lane & 7) ^ (lane >> 3);      // source chunk (inverse swz)
  const bf16_t* gA = A + (row0 + wave * 32 + srow) * K + schunk * 8;
  const bf16_t* gB = Bt + ((size_t)col0 + wave * 32 + srow) * K + schunk * 8;
  bf16_t* lA = As_ + wave * 2048 + lane * 8;  // + l*512 per load
  bf16_t* lB = Bs_ + wave * 2048 + lane * 8;

#define STAGE(j)                                           \
  do {                                                     \
    async_cp16(gA + (j)*64, lA);                           \
    async_cp16(gA + 8 * K + (j)*64, lA + 512);             \
    async_cp16(gA + 16 * K + (j)*64, lA + 1024);           \
    async_cp16(gA + 24 * K + (j)*64, lA + 1536);           \
    async_cp16(gB + (j)*64, lB);                           \
    async_cp16(gB + 8 * K + (j)*64, lB + 512);             \
    async_cp16(gB + 16 * K + (j)*64, lB + 1024);           \
    async_cp16(gB + 24 * K + (j)*64, lB + 1536);           \
  } while (0)
#define RD(base, row, kh)                                                    \
  (*(const bf16x8*)((const char*)(base) +                                    \
                    ((((row)*128) + ((kh)*64 + fkb)) ^ (((row)&7) << 4))))
#define VMCNT(n) asm volatile("s_waitcnt vmcnt(" #n ")")
#define LGKM0() asm volatile("s_waitcnt lgkmcnt(0)")
#define SCHED_FENCE() __builtin_amdgcn_sched_barrier(0)

  f32x4 acc[4][4] = {};
  bf16x8 a4[4], b4[4];

  // prologue: stage tile 0, wait, barrier
  STAGE(0);
  VMCNT(0);
  wg_barrier();
  SCHED_FENCE();

  for (int m = 0; m < KT; ++m) {
    // ---- kh = 0: 8 reads, 16 independent MFMAs ----
#pragma unroll
    for (int f = 0; f < 4; ++f) a4[f] = RD(As_, wm * 64 + f * 16 + fr, 0);
#pragma unroll
    for (int n = 0; n < 4; ++n) b4[n] = RD(Bs_, wn * 64 + n * 16 + fr, 0);
    __builtin_amdgcn_s_setprio(1);
#pragma unroll
    for (int f = 0; f < 4; ++f)
#pragma unroll
      for (int n = 0; n < 4; ++n)
        acc[f][n] = __builtin_amdgcn_mfma_f32_16x16x32_bf16(a4[f], b4[n], acc[f][n], 0, 0, 0);
    __builtin_amdgcn_s_setprio(0);
    // ---- kh = 1 ----
#pragma unroll
    for (int f = 0; f < 4; ++f) a4[f] = RD(As_, wm * 64 + f * 16 + fr, 1);
#pragma unroll
    for (int n = 0; n < 4; ++n) b4[n] = RD(Bs_, wn * 64 + n * 16 + fr, 1);
    __builtin_amdgcn_s_setprio(1);
#pragma unroll
    for (int f = 0; f < 4; ++f)
#pragma unroll
      for (int n = 0; n < 4; ++n)
        acc[f][n] = __builtin_amdgcn_mfma_f32_16x16x32_bf16(a4[f], b4[n], acc[f][n], 0, 0, 0);
    __builtin_amdgcn_s_setprio(0);
    // ---- tile boundary: drain my LDS reads, then overwrite buffer ----
    LGKM0();
    SCHED_FENCE();
    wg_barrier();  // all waves done reading tile m
    SCHED_FENCE();
    if (m + 1 < KT) STAGE(m + 1);  // WAR-safe overwrite
    VMCNT(0);                      // new tile landed
    wg_barrier();
    SCHED_FENCE();
  }
#undef STAGE
#undef RD
#undef VMCNT
#undef LGKM0
#undef SCHED_FENCE

  // ---- epilogue. C/D layout: col = lane&15, row = (lane>>4)*4 + reg ----
  const int lr = (lane >> 4) * 4;
  const int lc = lane & 15;
  const int gcol = col0 + wn * 64;  // aligned to one head (64)
  int which = 0;
  const float* bias = b0;
  int ocol = gcol;
  if constexpr (MODE == 0) {
    which = gcol >> 10;
    bias = (which == 0) ? b0 : (which == 1) ? b1 : b2;
    ocol = gcol - (which << 10);
  }
  const bool do_rope = (MODE == 0) && (which < 2);
  bf16_t* Cb = nullptr;
  float* Cf = nullptr;
  if constexpr (MODE == 0)
    Cb = (bf16_t*)((which == 0) ? O0 : (which == 1) ? O1 : O2);
  else
    Cf = (float*)O0;

#pragma unroll
  for (int mf = 0; mf < 4; ++mf) {
#pragma unroll
    for (int i = 0; i < 4; ++i) {
      const size_t grow = row0 + wm * 64 + mf * 16 + lr + i;
      float vv[4];
#pragma unroll
      for (int n = 0; n < 4; ++n) vv[n] = acc[mf][n][i] + bias[ocol + n * 16 + lc];
      if (do_rope) {
        // d(in-head) = n*16+lc; j = d>>1; partner d<32 ? d+32 (-sin) : d-32 (+sin)
        const int pos = (int)(grow & (size_t)(SEQ_L - 1));
        const float2* rp = rope + (size_t)pos * 32 + (lc >> 1);
        float rv[4];
#pragma unroll
        for (int n = 0; n < 4; ++n) {
          float2 cs = rp[n * 8];
          rv[n] = (n < 2) ? vv[n] * cs.x - vv[n + 2] * cs.y
                          : vv[n] * cs.x + vv[n - 2] * cs.y;
        }
#pragma unroll
        for (int n = 0; n < 4; ++n) vv[n] = rv[n];
      }
      const size_t cbase = grow * (size_t)DMODEL + ocol + lc;
      if constexpr (MODE == 1) {
#pragma unroll
        for (int n = 0; n < 4; ++n) Cf[cbase + n * 16] = vv[n];
      } else {
#pragma unroll
        for (int n = 0; n < 4; ++n) Cb[cbase + n * 16] = (bf16_t)vv[n];
      }
    }
  }
}

// ---------------- per-position head-mixing attention ----------------
__global__ __launch_bounds__(256) void attn_heads_k(const bf16_t* __restrict__ qb,
                                                    const bf16_t* __restrict__ kb,
                                                    const bf16_t* __restrict__ vb,
                                                    bf16_t* __restrict__ ob) {
  const int t = blockIdx.x * 256 + threadIdx.x;
  const int row = t >> 4;
  const int h = t & 15;
  const size_t rbase = (size_t)row * DMODEL;

  float q[HDIM];
#pragma unroll
  for (int j = 0; j < 8; ++j) {
    bf16x8 v8 = *(const bf16x8*)(qb + rbase + h * HDIM + j * 8);
#pragma unroll
    for (int u = 0; u < 8; ++u) q[j * 8 + u] = (float)v8[u];
  }
  float s[NHEAD];
#pragma unroll
  for (int e = 0; e < NHEAD; ++e) {
    float a = 0.f;
#pragma unroll
    for (int j = 0; j < 8; ++j) {
      bf16x8 k8 = *(const bf16x8*)(kb + rbase + e * HDIM + j * 8);
#pragma unroll
      for (int u = 0; u < 8; ++u) a += q[j * 8 + u] * (float)k8[u];
    }
    s[e] = a * 0.125f;
  }
  float mx = s[0];
#pragma unroll
  for (int e = 1; e < NHEAD; ++e) mx = fmaxf(mx, s[e]);
  float sum = 0.f;
#pragma unroll
  for (int e = 0; e < NHEAD; ++e) {
    s[e] = __expf(s[e] - mx);
    sum += s[e];
  }
  const float inv = 1.f / sum;
  float o[HDIM] = {};
#pragma unroll
  for (int e = 0; e < NHEAD; ++e) {
    const float w = s[e] * inv;
#pragma unroll
    for (int j = 0; j < 8; ++j) {
      bf16x8 v8 = *(const bf16x8*)(vb + rbase + e * HDIM + j * 8);
#pragma unroll
      for (int u = 0; u < 8; ++u) o[j * 8 + u] += w * (float)v8[u];
    }
  }
#pragma unroll
  for (int j = 0; j < 8; ++j) {
    bf16x8 st;
#pragma unroll
    for (int u = 0; u < 8; ++u) st[u] = (__bf16)o[j * 8 + u];
    *(bf16x8*)(ob + rbase + h * HDIM + j * 8) = st;
  }
}

extern "C" void kernel_launch(void* const* d_in, const int* in_sizes, int n_in,
                              void* d_out, int out_size, void* d_ws, size_t ws_size,
                              hipStream_t stream) {
  const float* x = (const float*)d_in[0];
  const float* Wq = (const float*)d_in[1];
  const float* bq = (const float*)d_in[2];
  const float* Wk = (const float*)d_in[3];
  const float* bk = (const float*)d_in[4];
  const float* Wv = (const float*)d_in[5];
  const float* bv = (const float*)d_in[6];
  const float* Wo = (const float*)d_in[7];
  const float* bo = (const float*)d_in[8];

  const int M = MROWS, N = DMODEL, K = DMODEL;

  char* p = (char*)d_ws;
  bf16_t* xb = (bf16_t*)p;    p += (size_t)M * K * 2;      // 32 MB
  bf16_t* Wqkvt = (bf16_t*)p; p += (size_t)3 * N * K * 2;  // 6 MB (q|k|v rows)
  bf16_t* Wot = (bf16_t*)p;   p += (size_t)N * K * 2;      // 2 MB
  bf16_t* qb = (bf16_t*)p;    p += (size_t)M * N * 2;      // 32 MB each
  bf16_t* kb = (bf16_t*)p;    p += (size_t)M * N * 2;
  bf16_t* vb = (bf16_t*)p;    p += (size_t)M * N * 2;
  bf16_t* ab = (bf16_t*)p;    p += (size_t)M * N * 2;
  float2* rope = (float2*)p;  p += (size_t)SEQ_L * 32 * sizeof(float2);  // 2 MB

  bf16_t* Wqt = Wqkvt;
  bf16_t* Wkt = Wqkvt + (size_t)N * K;
  bf16_t* Wvt = Wqkvt + (size_t)2 * N * K;

  f32_to_bf16_k<<<(M * K) / (256 * 8), 256, 0, stream>>>(x, xb, M * K);
  w_to_bt_k<<<dim3(32, 32, 4), dim3(32, 8), 0, stream>>>(Wq, Wk, Wv, Wo, Wqt, Wkt, Wvt, Wot);
  rope_tab_k<<<(SEQ_L * 32) / 256, 256, 0, stream>>>(rope);

  // fused QKV: C(16384 x 3072), 128 x 24 blocks of 128^2
  gemm128<0><<<dim3(M / 128, (3 * N) / 128), 256, 0, stream>>>(
      xb, Wqkvt, bq, bk, bv, rope, (void*)qb, (void*)kb, (void*)vb);
  attn_heads_k<<<(M * NHEAD) / 256, 256, 0, stream>>>(qb, kb, vb, ab);
  gemm128<1><<<dim3(M / 128, N / 128), 256, 0, stream>>>(
      ab, Wot, bo, nullptr, nullptr, nullptr, d_out, nullptr, nullptr);
}